// Round 1
// baseline (700.184 us; speedup 1.0000x reference)
//
#include <hip/hip_runtime.h>
#include <hip/hip_bf16.h>
#include <math.h>

#define SEQ    2048
#define HIDDEN 4096
#define NH     32
#define NKV    8
#define HD     128
#define QKV_N  6144   // 4096 q + 1024 k + 1024 v

typedef __attribute__((ext_vector_type(8))) short bf16x8;
typedef __attribute__((ext_vector_type(4))) float f32x4;
typedef unsigned short u16;
typedef unsigned int u32;

#define VMCNT(n) asm volatile("s_waitcnt vmcnt(" #n ")" ::: "memory")

__device__ inline void gl_lds16(const void* g, void* lds) {
  __builtin_amdgcn_global_load_lds((const __attribute__((address_space(1))) void*)g,
                                   (__attribute__((address_space(3))) void*)lds, 16, 0, 0);
}

__device__ inline void tile_barrier() {
  __builtin_amdgcn_sched_barrier(0);
  __builtin_amdgcn_s_barrier();
  __builtin_amdgcn_sched_barrier(0);
}

__device__ inline u16 f2bf(float f) {
  __hip_bfloat16 h = __float2bfloat16(f);
  return *(u16*)&h;
}
__device__ inline float bf2f(u16 u) {
  __hip_bfloat16 h = *(__hip_bfloat16*)&u;
  return __bfloat162float(h);
}

// ---------------- fp32 -> bf16 conversion (8 elements / thread) ----------------
__global__ void cvt_f32_bf16(const float* __restrict__ src, u16* __restrict__ dst, int n8) {
  int i = blockIdx.x * blockDim.x + threadIdx.x;
  if (i >= n8) return;
  const float4* s = (const float4*)src + (size_t)i * 2;
  float4 a = s[0], b = s[1];
  float v[8] = {a.x, a.y, a.z, a.w, b.x, b.y, b.z, b.w};
  union { u16 o[8]; uint4 u; } pk;
#pragma unroll
  for (int j = 0; j < 8; j++) pk.o[j] = f2bf(v[j]);
  *(uint4*)(dst + (size_t)i * 8) = pk.u;
}

// ---------------- bf16 GEMM, C = A * B^T  (A: MxK, B: NxK, both row-major) -----------------
// Ring-4 pipelined structure (T1+T2+T3+T4+T5):
//  - tile 256 x (NF*64), BK=32, 8 waves (2M x 4N), 512 threads, LDS = 4 ring buffers
//  - stage tile t+3 while computing tile t (writes the buffer freed at tile t-1)
//  - counted vmcnt at each tile boundary (8/6 steady; never 0 until epilogue drain)
//  - LDS XOR swizzle slot^=(row&3)^((row>>2)&1) applied on BOTH sides:
//    inverse-permuted per-lane GLOBAL source (global_load_lds dest stays linear) +
//    swizzled ds_read address -> conflict-free ds_read_b128 (uniform 8 lanes / 4-bank group)
//  - one raw s_barrier per K-tile, pinned with sched_barrier(0); setprio(1) around MFMAs
template <int OUTF32, int NF>
__global__ __launch_bounds__(512, 2) void gemm_bt2(const u16* __restrict__ A,
                                                   const u16* __restrict__ B,
                                                   void* __restrict__ Cout,
                                                   int M, int N, int K) {
  __shared__ __align__(16) u16 Abuf[4][256 * 32];
  __shared__ __align__(16) u16 Bbuf[4][NF * 64 * 32];
  const int tid = threadIdx.x;
  const int w = tid >> 6, lane = tid & 63;
  const int quad = lane >> 4, l16 = lane & 15;
  const int wm = w >> 2, wn = w & 3;
  constexpr int BN = NF * 64;

  // XCD-bijective block swizzle: consecutive work chunks per XCD -> A-panel L2 reuse
  const int nwg = gridDim.x;
  const int bid = blockIdx.x;
  const int qq = nwg >> 3, rr8 = nwg & 7;
  const int xcd = bid & 7, loc = bid >> 3;
  const int wg = (xcd < rr8 ? xcd * (qq + 1) : rr8 * (qq + 1) + (xcd - rr8) * qq) + loc;
  const int nbx = N / BN;
  const int m0 = (wg / nbx) * 256;
  const int n0 = (wg % nbx) * BN;

  // staging: lane covers LDS (row = w*16 + lane>>2, slot' = lane&3); source column is
  // slot'^swz(row) so that the linear DMA write realizes the swizzled layout
  const int srow = lane >> 2;
  const int sswz = ((lane >> 2) & 3) ^ ((lane >> 4) & 1);
  const int scol = ((lane & 3) ^ sswz) << 3;
  const u16* aG = A + (size_t)(m0 + w * 16 + srow) * K + scol;
  const u16* bG = B + (size_t)(n0 + w * 16 + srow) * K + scol;
  const int NT = K >> 5;

  // fragment-read swizzle (row&3 == l16&3, row bit2 == l16 bit2 for all frags)
  const int swzr = (l16 & 3) ^ ((l16 >> 2) & 1);
  const int kslot = (quad ^ swzr) << 3;

  f32x4 acc[8][NF] = {};

  auto stage = [&](int t) {
    const int b = t & 3;
    const size_t k0 = (size_t)t << 5;
    gl_lds16(aG + k0,                   &Abuf[b][(w * 16) * 32]);
    gl_lds16(aG + k0 + (size_t)128 * K, &Abuf[b][(128 + w * 16) * 32]);
    gl_lds16(bG + k0,                   &Bbuf[b][(w * 16) * 32]);
    if constexpr (NF == 4)
      gl_lds16(bG + k0 + (size_t)128 * K, &Bbuf[b][(128 + w * 16) * 32]);
  };

  stage(0); stage(1); stage(2);
  if constexpr (NF == 4) { VMCNT(8); } else { VMCNT(6); }   // tile 0 landed; 1,2 in flight
  tile_barrier();

  for (int t = 0; t < NT; ++t) {
    const int b = t & 3;
    if (t + 3 < NT) stage(t + 3);

    bf16x8 af[8], bfr[NF];
#pragma unroll
    for (int f = 0; f < 8; ++f)
      af[f] = *(const bf16x8*)&Abuf[b][(wm * 128 + f * 16 + l16) * 32 + kslot];
#pragma unroll
    for (int nf = 0; nf < NF; ++nf)
      bfr[nf] = *(const bf16x8*)&Bbuf[b][(wn * (NF * 16) + nf * 16 + l16) * 32 + kslot];

    __builtin_amdgcn_s_setprio(1);
#pragma unroll
    for (int f = 0; f < 8; ++f)
#pragma unroll
      for (int nf = 0; nf < NF; ++nf)
        acc[f][nf] = __builtin_amdgcn_mfma_f32_16x16x32_bf16(af[f], bfr[nf], acc[f][nf], 0, 0, 0);
    __builtin_amdgcn_s_setprio(0);

    if (t < NT - 1) {
      if (t + 3 < NT) {            // steady: tiles t+2,t+3 stay in flight, t+1 landed
        if constexpr (NF == 4) { VMCNT(8); } else { VMCNT(6); }
      } else if (t + 3 == NT) {    // drain: only tile NT-1 stays in flight
        if constexpr (NF == 4) { VMCNT(4); } else { VMCNT(3); }
      } else {                     // t == NT-2: last tile must be landed
        VMCNT(0);
      }
      tile_barrier();
    }
  }

#pragma unroll
  for (int f = 0; f < 8; ++f)
#pragma unroll
    for (int nf = 0; nf < NF; ++nf)
#pragma unroll
      for (int r = 0; r < 4; ++r) {
        int row = m0 + wm * 128 + f * 16 + quad * 4 + r;
        int col = n0 + wn * (NF * 16) + nf * 16 + l16;
        float v = acc[f][nf][r];
        if (OUTF32) ((float*)Cout)[(size_t)row * N + col] = v;
        else        ((u16*)Cout)[(size_t)row * N + col] = f2bf(v);
      }
}

// ---------------- RoPE in-place on bf16 qkv buffer (q heads 0..31, k heads 0..7) ------------
__global__ void rope_kernel(u16* __restrict__ qkv, const int* __restrict__ pos_ids) {
  int idx = blockIdx.x * blockDim.x + threadIdx.x;
  int d = idx & 63;
  int h = (idx >> 6) % 40;
  int s = idx / (64 * 40);
  if (s >= SEQ) return;
  int off = (h < NH) ? h * HD : HIDDEN + (h - NH) * HD;
  u16* base = qkv + (size_t)s * QKV_N + off;
  float inv_freq = powf(10000.0f, -(float)d * (1.0f / 64.0f));
  float ang = (float)pos_ids[s] * inv_freq;
  float sn, cs;
  sincosf(ang, &sn, &cs);
  float x1 = bf2f(base[d]);
  float x2 = bf2f(base[d + 64]);
  base[d]      = f2bf(x1 * cs - x2 * sn);
  base[d + 64] = f2bf(x2 * cs + x1 * sn);
}

// ---------------- V transpose: qkv v-slice [s][c] -> vt[c][s]  (c = kvh*128+d, 1024 x 2048) --
__global__ __launch_bounds__(256) void transpose_v(const u16* __restrict__ qkv,
                                                   u16* __restrict__ vt) {
  __shared__ u16 t[64][72];
  const int s0 = blockIdx.x * 64, c0 = blockIdx.y * 64;
  const int tid = threadIdx.x;
#pragma unroll
  for (int i = 0; i < 2; i++) {
    int r = (tid >> 3) + i * 32;
    int c = (tid & 7) * 8;
    *(uint4*)&t[r][c] = *(const uint4*)&qkv[(size_t)(s0 + r) * QKV_N + 5120 + c0 + c];
  }
  __syncthreads();
#pragma unroll
  for (int i = 0; i < 2; i++) {
    int c = (tid >> 3) + i * 32;
    int s = (tid & 7) * 8;
    union { uint4 u; u16 e[8]; } o;
#pragma unroll
    for (int j = 0; j < 8; j++) o.e[j] = t[s + j][c];
    *(uint4*)&vt[(size_t)(c0 + c) * SEQ + s0 + s] = o.u;
  }
}

// ---------------- flash attention v5: S^T form, shuffle-based P transform, split-K ----------
// Block = 2 waves on the same (32 q-rows, head); wave 0 even key-tiles, wave 1 odd.
// S^T = K*Q^T (mfma A=K, B=Q) -> C-layout col=q(l16), row=key(quad*4+r).
// P^T enters PV as B-operand via quad-permutation (__shfl), NO LDS in the loop.
// O^T = V^T*P^T accumulated in C-layout (col=q). Fixed softmax shift exp2(s*c-32):
// partials combine by pure addition. Only the epilogue combine uses LDS + 1 barrier.
// kvh = blk&7 keeps one kv-head per XCD (L2 affinity); longest q-tiles first.
__global__ __launch_bounds__(128, 3) void attn_kernel(const u16* __restrict__ qkv,
                                                      const u16* __restrict__ vt,
                                                      u16* __restrict__ attn_out) {
  __shared__ __align__(16) float Ex[32 * 132];   // [q:32][d:128 +pad] + col128 = lsum
  const int blk = blockIdx.x;
  const int kvh = blk & 7;             // XCD affinity: one kv-head per XCD
  const int hg = (blk >> 3) & 3;
  const int it = 63 - (blk >> 5);      // longest q-tiles dispatched first
  const int h  = kvh * 4 + hg;
  const int tid = threadIdx.x;
  const int wave = tid >> 6, lane = tid & 63;
  const int quad = lane >> 4, l16 = lane & 15;
  const int q0 = it * 32;

  const float c = 0.08838834764831845f * 1.4426950408889634f; // D^-0.5 * log2e

  // Q B-fragments: n=q(l16), k=d(quad*8+j); 2 m-tiles x 4 d-chunks
  bf16x8 qf[2][4];
#pragma unroll
  for (int m = 0; m < 2; m++)
#pragma unroll
    for (int dc = 0; dc < 4; dc++)
      qf[m][dc] = *(const bf16x8*)(qkv + (size_t)(q0 + m * 16 + l16) * QKV_N + h * HD + dc * 32 + quad * 8);

  // K A-fragment pointers: m=key(st*16+l16), k=d; start at this wave's first tile
  const u16* kp[4];
#pragma unroll
  for (int st = 0; st < 4; st++)
    kp[st] = qkv + (size_t)(wave * 64 + st * 16 + l16) * QKV_N + HIDDEN + kvh * HD + quad * 8;
  // V^T A-fragment pointers: m=d(dt*16+l16), k=key
  const u16* vp[8];
#pragma unroll
  for (int dt = 0; dt < 8; dt++)
    vp[dt] = vt + (size_t)(kvh * HD + dt * 16 + l16) * SEQ + wave * 64 + quad * 8;

  float lsum[2] = {0.f, 0.f};
  f32x4 o[2][8] = {};

  const int srcA = ((lane >> 4) & 1) * 32 + l16;   // quad 0 or 2, same l16
  const int srcB = srcA + 16;                      // quad 1 or 3
  const bool hi = quad >= 2;

  const int n_kt = (q0 + 95) >> 6;   // 64-key tiles covering 0 .. q0+31
  for (int kt = wave; kt < n_kt; kt += 2) {
    const bool last = (kt == n_kt - 1);

    // ---- S^T = K Q^T over 64 keys; softmax + pack to bf16 pairs ----
    u32 pk[2][4][2];
#pragma unroll
    for (int st = 0; st < 4; st++) {
      bf16x8 kst[4];
#pragma unroll
      for (int dc = 0; dc < 4; dc++) kst[dc] = *(const bf16x8*)(kp[st] + dc * 32);
      f32x4 s[2] = {};
#pragma unroll
      for (int dc = 0; dc < 4; dc++)
#pragma unroll
        for (int m = 0; m < 2; m++)
          s[m] = __builtin_amdgcn_mfma_f32_16x16x32_bf16(kst[dc], qf[m][dc], s[m], 0, 0, 0);
#pragma unroll
      for (int m = 0; m < 2; m++) {
        float pr[4];
#pragma unroll
        for (int r = 0; r < 4; r++) {
          float v = fmaf(s[m][r], c, -32.0f);
          if (last) {
            int key = kt * 64 + st * 16 + quad * 4 + r;
            if (key > q0 + m * 16 + l16) v = -1e30f;
          }
          pr[r] = exp2f(v);
          lsum[m] += pr[r];
        }
        pk[m][st][0] = ((u32)f2bf(pr[1]) << 16) | f2bf(pr[0]);
        pk[m][st][1] = ((u32)f2bf(pr[3]) << 16) | f2bf(pr[2]);
      }
    }

    // ---- P^T B-fragments via quad permutation (no LDS) ----
    bf16x8 pf[2][2];
#pragma unroll
    for (int m = 0; m < 2; m++)
#pragma unroll
      for (int kc = 0; kc < 2; kc++) {
        union { u32 w[4]; bf16x8 v; } u;
        u32 a0 = (u32)__shfl((int)pk[m][2 * kc][0],     srcA);
        u32 b0 = (u32)__shfl((int)pk[m][2 * kc + 1][0], srcA);
        u32 a1 = (u32)__shfl((int)pk[m][2 * kc][1],     srcA);
        u32 b1 = (u32)__shfl((int)pk[m][2 * kc + 1][1], srcA);
        u32 a2 = (u32)__shfl((int)pk[m][2 * kc][0],     srcB);
        u32 b2 = (u32)__shfl((int)pk[m][2 * kc + 1][0], srcB);
        u32 a3 = (u32)__shfl((int)pk[m][2 * kc][1],     srcB);
        u32 b3 = (u32)__shfl((int)pk[m][2 * kc + 1][1], srcB);
        u.w[0] = hi ? b0 : a0;
        u.w[1] = hi ? b1 : a1;
        u.w[2] = hi ? b2 : a2;
        u.w[3] = hi ? b3 : a3;
        pf[m][kc] = u.v;
      }

    // ---- O^T += V^T P^T ----
#pragma unroll
    for (int dt = 0; dt < 8; dt++) {
      bf16x8 vf0 = *(const bf16x8*)(vp[dt]);
      bf16x8 vf1 = *(const bf16x8*)(vp[dt] + 32);
#pragma unroll
      for (int m = 0; m < 2; m++) {
        o[m][dt] = __builtin_amdgcn_mfma_f32_16x16x32_bf16(vf0, pf[m][0], o[m][dt], 0, 0, 0);
        o[m][dt] = __builtin_amdgcn_mfma_f32_16x16x32_bf16(vf1, pf[m][1], o[m][dt], 0, 0, 0);
      }
    }

#pragma unroll
    for (int st = 0; st < 4; st++) kp[st] += (size_t)128 * QKV_N;   // skip 2 tiles
#pragma unroll
    for (int dt = 0; dt < 8; dt++) vp[dt] += 128;
  }

  // ---- reduce lsum across the 4 quads (q is per-lane l16) ----
#pragma unroll
  for (int m = 0; m < 2; m++) {
    lsum[m] += __shfl_xor(lsum[m], 16);
    lsum[m] += __shfl_xor(lsum[m], 32);
  }

  // ---- combine the two waves' partials (pure addition; fixed shift) ----
  if (wave == 1) {
#pragma unroll
    for (int m = 0; m < 2; m++) {
#pragma unroll
      for (int dt = 0; dt < 8; dt++)
        *(f32x4*)&Ex[(m * 16 + l16) * 132 + dt * 16 + quad * 4] = o[m][dt];
      if (lane < 16) Ex[(m * 16 + l16) * 132 + 128] = lsum[m];
    }
  }
  __syncthreads();
  if (wave == 0) {
#pragma unroll
    for (int m = 0; m < 2; m++) {
      float lt = lsum[m] + Ex[(m * 16 + l16) * 132 + 128];
      float inv = 1.0f / lt;
      size_t base = (size_t)(q0 + m * 16 + l16) * HIDDEN + h * HD;
#pragma unroll
      for (int dt = 0; dt < 8; dt++) {
        f32x4 p = *(const f32x4*)&Ex[(m * 16 + l16) * 132 + dt * 16 + quad * 4];
        float v0 = (o[m][dt][0] + p[0]) * inv;
        float v1 = (o[m][dt][1] + p[1]) * inv;
        float v2 = (o[m][dt][2] + p[2]) * inv;
        float v3 = (o[m][dt][3] + p[3]) * inv;
        u32 w0 = ((u32)f2bf(v1) << 16) | f2bf(v0);
        u32 w1 = ((u32)f2bf(v3) << 16) | f2bf(v2);
        uint2 wv; wv.x = w0; wv.y = w1;
        *(uint2*)&attn_out[base + dt * 16 + quad * 4] = wv;
      }
    }
  }
}

// ---------------- launch ----------------
extern "C" void kernel_launch(void* const* d_in, const int* in_sizes, int n_in,
                              void* d_out, int out_size, void* d_ws, size_t ws_size,
                              hipStream_t stream) {
  const float* x  = (const float*)d_in[0];
  const int* pos  = (const int*)d_in[1];
  const float* Wq = (const float*)d_in[3];
  const float* Wk = (const float*)d_in[4];
  const float* Wv = (const float*)d_in[5];
  const float* Wo = (const float*)d_in[6];
  float* out = (float*)d_out;

  u16* x_bf    = (u16*)d_ws;                                  // 2048*4096
  u16* Wqkv_bf = x_bf + (size_t)SEQ * HIDDEN;                 // 6144*4096
  u16* qkv_bf  = Wqkv_bf + (size_t)QKV_N * HIDDEN;            // 2048*6144
  u16* attn_bf = qkv_bf + (size_t)SEQ * QKV_N;                // 2048*4096
  u16* Wo_bf   = attn_bf + (size_t)SEQ * HIDDEN;              // 4096*4096
  u16* vt_bf   = x_bf;   // reuse x_bf region (dead after gemm1); 1024*2048 fits

  auto cvt = [&](const float* s, u16* d, size_t n) {
    int n8 = (int)(n / 8);
    cvt_f32_bf16<<<(n8 + 255) / 256, 256, 0, stream>>>(s, d, n8);
  };
  cvt(x,  x_bf,    (size_t)SEQ * HIDDEN);
  cvt(Wq, Wqkv_bf,                         (size_t)4096 * 4096);
  cvt(Wk, Wqkv_bf + (size_t)4096 * 4096,   (size_t)1024 * 4096);
  cvt(Wv, Wqkv_bf + (size_t)5120 * 4096,   (size_t)1024 * 4096);
  cvt(Wo, Wo_bf,   (size_t)4096 * 4096);

  // GEMM1: 2048x6144x4096, BN=256 -> 8*24 = 192 blocks (one round, no tail)
  gemm_bt2<0, 4><<<dim3((SEQ / 256) * (QKV_N / 256)), 512, 0, stream>>>(
      x_bf, Wqkv_bf, qkv_bf, SEQ, QKV_N, HIDDEN);

  int rope_threads = SEQ * 40 * 64;
  rope_kernel<<<rope_threads / 256, 256, 0, stream>>>(qkv_bf, pos);

  dim3 gt(SEQ / 64, 1024 / 64);
  transpose_v<<<gt, 256, 0, stream>>>(qkv_bf, vt_bf);

  attn_kernel<<<2048, 128, 0, stream>>>(qkv_bf, vt_bf, attn_bf);

  // GEMM3: 2048x4096x4096, BN=128 -> 8*32 = 256 blocks (full chip)
  gemm_bt2<1, 2><<<dim3((SEQ / 256) * (HIDDEN / 128)), 512, 0, stream>>>(
      attn_bf, Wo_bf, out, SEQ, HIDDEN, HIDDEN);
}

// Round 2
// 629.886 us; speedup vs baseline: 1.1116x; 1.1116x over previous
//
#include <hip/hip_runtime.h>
#include <hip/hip_bf16.h>
#include <math.h>

#define SEQ    2048
#define HIDDEN 4096
#define NH     32
#define NKV    8
#define HD     128
#define QKV_N  6144   // 4096 q + 1024 k + 1024 v

typedef __attribute__((ext_vector_type(8))) short bf16x8;
typedef __attribute__((ext_vector_type(4))) float f32x4;
typedef unsigned short u16;
typedef unsigned int u32;

#define VMCNT(n) asm volatile("s_waitcnt vmcnt(" #n ")" ::: "memory")
#define LGKM0 do { asm volatile("s_waitcnt lgkmcnt(0)" ::: "memory"); \
                   __builtin_amdgcn_sched_barrier(0); } while (0)

__device__ inline void gl_lds16(const void* g, void* lds) {
  __builtin_amdgcn_global_load_lds((const __attribute__((address_space(1))) void*)g,
                                   (__attribute__((address_space(3))) void*)lds, 16, 0, 0);
}

__device__ inline void tile_bar() {
  __builtin_amdgcn_sched_barrier(0);
  __builtin_amdgcn_s_barrier();
  __builtin_amdgcn_sched_barrier(0);
}

__device__ inline u16 f2bf(float f) {
  __hip_bfloat16 h = __float2bfloat16(f);
  return *(u16*)&h;
}
__device__ inline float bf2f(u16 u) {
  __hip_bfloat16 h = *(__hip_bfloat16*)&u;
  return __bfloat162float(h);
}

// ---------------- fp32 -> bf16 conversion (8 elements / thread) ----------------
__global__ void cvt_f32_bf16(const float* __restrict__ src, u16* __restrict__ dst, int n8) {
  int i = blockIdx.x * blockDim.x + threadIdx.x;
  if (i >= n8) return;
  const float4* s = (const float4*)src + (size_t)i * 2;
  float4 a = s[0], b = s[1];
  float v[8] = {a.x, a.y, a.z, a.w, b.x, b.y, b.z, b.w};
  union { u16 o[8]; uint4 u; } pk;
#pragma unroll
  for (int j = 0; j < 8; j++) pk.o[j] = f2bf(v[j]);
  *(uint4*)(dst + (size_t)i * 8) = pk.u;
}

// ---------------- bf16 GEMM, C = A * B^T  (A: MxK, B: NxK, both row-major) -----------------
// Ring-buffered, two-fine-phase per K-tile schedule:
//   BM=256, BN=NF*64, BK=32, 8 waves (2M x 4N), 512 threads.
//   NF=3: ring-4 LDS (128 KiB), stage t+3 while computing t, vmcnt(8) steady.
//   NF=2: ring-3 LDS (72 KiB, 2 blocks/CU), stage t+2, vmcnt(3) steady.
//   Per K-tile: P0 {read af[0..3]+bf[all] | stage A(t+R-1) | bar | lgkm0 | 4xNF MFMA | bar}
//               P1 {read af[4..7]         | stage B(t+R-1) | bar | lgkm0 | 4xNF MFMA | vmcnt | bar}
//   B-fragments held in registers across both phases. No LDS swizzle needed: BK=32 row
//   stride = 64B -> bank group (l16&1)*4+quad is uniform 8 lanes/group (conflict-free).
template <int OUTF32, int NF>
__global__ __launch_bounds__(512, NF == 2 ? 4 : 2)
void gemm8p(const u16* __restrict__ A, const u16* __restrict__ B,
            void* __restrict__ Cout, int M, int N, int K) {
  constexpr int RING  = (NF == 2) ? 3 : 4;
  constexpr int BROWS = (NF == 2) ? 128 : 256;   // NF=3 pads to 256 (rows 192..255 unused)
  constexpr int A_ELE = 256 * 32;
  constexpr int B_ELE = BROWS * 32;
  __shared__ __align__(16) u16 Ab[RING * A_ELE];
  __shared__ __align__(16) u16 Bb[RING * B_ELE];

  const int tid = threadIdx.x;
  const int w = tid >> 6, lane = tid & 63;
  const int quad = lane >> 4, l16 = lane & 15;
  const int wm = w >> 2, wn = w & 3;
  constexpr int BN = NF * 64;

  // block mapping: XCD (bid&7) owns 4 contiguous n-panels (B resident in its L2), all m.
  const int bid = blockIdx.x;
  const int nbn = N / BN;                       // 32 for both GEMMs here
  const int npx = nbn >> 3;                     // n-panels per XCD
  const int n_idx = (bid & 7) * npx + ((bid >> 3) % npx);
  const int m_idx = bid / (8 * npx);
  const int m0 = m_idx * 256, n0 = n_idx * BN;

  // staging: per gl_lds16 call a wave covers 16 rows x 32 cols (1024B), lane l ->
  // row +(l>>2), 16B slot (l&3). Linear layout (matches DMA lane order).
  const u16* aS = A + (size_t)(m0 + w * 16 + (lane >> 2)) * K + (lane & 3) * 8;
  const u16* bS = B + (size_t)(n0 + w * 16 + (lane >> 2)) * K + (lane & 3) * 8;
  const size_t boff2 = (size_t)((NF == 3 && w >= 4) ? 0 : 128) * K;  // NF=3 tail dup

  const int NT = K >> 5;

  f32x4 acc[8][NF] = {};

  auto stageA = [&](int t) {
    const int b = t % RING;
    gl_lds16(aS + (size_t)t * 32, &Ab[b * A_ELE + (w * 16) * 32]);
    gl_lds16(aS + (size_t)128 * K + (size_t)t * 32, &Ab[b * A_ELE + (128 + w * 16) * 32]);
  };
  auto stageB = [&](int t) {
    const int b = t % RING;
    gl_lds16(bS + (size_t)t * 32, &Bb[b * B_ELE + (w * 16) * 32]);
    if constexpr (NF == 3)
      gl_lds16(bS + boff2 + (size_t)t * 32, &Bb[b * B_ELE + (128 + w * 16) * 32]);
    if constexpr (NF == 4)
      gl_lds16(bS + (size_t)128 * K + (size_t)t * 32, &Bb[b * B_ELE + (128 + w * 16) * 32]);
  };

  // prologue: fill the pipeline (RING-1 tiles in flight), wait only for tile 0
  if constexpr (NF == 2) {
    stageA(0); stageB(0); stageA(1); stageB(1);
    VMCNT(3);
  } else {
    stageA(0); stageB(0); stageA(1); stageB(1); stageA(2); stageB(2);
    VMCNT(8);
  }
  tile_bar();

  for (int t = 0; t < NT; ++t) {
    const int b = t % RING;
    const u16* Abt = &Ab[b * A_ELE];
    const u16* Bbt = &Bb[b * B_ELE];

    // ---- phase 0: af[0..3] + all B frags; stage A of tile t+RING-1 ----
    bf16x8 af0[4], bfv[NF];
#pragma unroll
    for (int f = 0; f < 4; ++f)
      af0[f] = *(const bf16x8*)&Abt[(wm * 128 + f * 16 + l16) * 32 + quad * 8];
#pragma unroll
    for (int n = 0; n < NF; ++n)
      bfv[n] = *(const bf16x8*)&Bbt[(wn * (NF * 16) + n * 16 + l16) * 32 + quad * 8];
    if (t + RING - 1 < NT) stageA(t + RING - 1);
    tile_bar();
    LGKM0;
    __builtin_amdgcn_s_setprio(1);
#pragma unroll
    for (int f = 0; f < 4; ++f)
#pragma unroll
      for (int n = 0; n < NF; ++n)
        acc[f][n] = __builtin_amdgcn_mfma_f32_16x16x32_bf16(af0[f], bfv[n], acc[f][n], 0, 0, 0);
    __builtin_amdgcn_s_setprio(0);
    tile_bar();

    // ---- phase 1: af[4..7]; stage B of tile t+RING-1 ----
    bf16x8 af1[4];
#pragma unroll
    for (int f = 0; f < 4; ++f)
      af1[f] = *(const bf16x8*)&Abt[(wm * 128 + (4 + f) * 16 + l16) * 32 + quad * 8];
    if (t + RING - 1 < NT) stageB(t + RING - 1);
    tile_bar();
    LGKM0;
    __builtin_amdgcn_s_setprio(1);
#pragma unroll
    for (int f = 0; f < 4; ++f)
#pragma unroll
      for (int n = 0; n < NF; ++n)
        acc[4 + f][n] = __builtin_amdgcn_mfma_f32_16x16x32_bf16(af1[f], bfv[n], acc[4 + f][n], 0, 0, 0);
    __builtin_amdgcn_s_setprio(0);

    // ---- K-tile boundary: counted wait (never drain to 0 mid-loop) ----
    if (t < NT - 1) {
      if constexpr (NF == 2) {
        if (t + 2 < NT) { VMCNT(3); } else { VMCNT(0); }
      } else {
        if (t + 3 < NT)       { VMCNT(8); }
        else if (t + 3 == NT) { VMCNT(4); }
        else                  { VMCNT(0); }
      }
      tile_bar();
    }
  }

#pragma unroll
  for (int f = 0; f < 8; ++f)
#pragma unroll
    for (int n = 0; n < NF; ++n)
#pragma unroll
      for (int r = 0; r < 4; ++r) {
        int row = m0 + wm * 128 + f * 16 + quad * 4 + r;
        int col = n0 + wn * (NF * 16) + n * 16 + l16;
        float v = acc[f][n][r];
        if (OUTF32) ((float*)Cout)[(size_t)row * N + col] = v;
        else        ((u16*)Cout)[(size_t)row * N + col] = f2bf(v);
      }
}

// ---------------- RoPE in-place on bf16 qkv buffer (q heads 0..31, k heads 0..7) ------------
__global__ void rope_kernel(u16* __restrict__ qkv, const int* __restrict__ pos_ids) {
  int idx = blockIdx.x * blockDim.x + threadIdx.x;
  int d = idx & 63;
  int h = (idx >> 6) % 40;
  int s = idx / (64 * 40);
  if (s >= SEQ) return;
  int off = (h < NH) ? h * HD : HIDDEN + (h - NH) * HD;
  u16* base = qkv + (size_t)s * QKV_N + off;
  float inv_freq = powf(10000.0f, -(float)d * (1.0f / 64.0f));
  float ang = (float)pos_ids[s] * inv_freq;
  float sn, cs;
  sincosf(ang, &sn, &cs);
  float x1 = bf2f(base[d]);
  float x2 = bf2f(base[d + 64]);
  base[d]      = f2bf(x1 * cs - x2 * sn);
  base[d + 64] = f2bf(x2 * cs + x1 * sn);
}

// ---------------- V transpose: qkv v-slice [s][c] -> vt[c][s]  (c = kvh*128+d, 1024 x 2048) --
__global__ __launch_bounds__(256) void transpose_v(const u16* __restrict__ qkv,
                                                   u16* __restrict__ vt) {
  __shared__ u16 t[64][72];
  const int s0 = blockIdx.x * 64, c0 = blockIdx.y * 64;
  const int tid = threadIdx.x;
#pragma unroll
  for (int i = 0; i < 2; i++) {
    int r = (tid >> 3) + i * 32;
    int c = (tid & 7) * 8;
    *(uint4*)&t[r][c] = *(const uint4*)&qkv[(size_t)(s0 + r) * QKV_N + 5120 + c0 + c];
  }
  __syncthreads();
#pragma unroll
  for (int i = 0; i < 2; i++) {
    int c = (tid >> 3) + i * 32;
    int s = (tid & 7) * 8;
    union { uint4 u; u16 e[8]; } o;
#pragma unroll
    for (int j = 0; j < 8; j++) o.e[j] = t[s + j][c];
    *(uint4*)&vt[(size_t)(c0 + c) * SEQ + s0 + s] = o.u;
  }
}

// ---------------- flash attention v5: S^T form, shuffle-based P transform, split-K ----------
// Block = 2 waves on the same (32 q-rows, head); wave 0 even key-tiles, wave 1 odd.
// S^T = K*Q^T (mfma A=K, B=Q) -> C-layout col=q(l16), row=key(quad*4+r).
// P^T enters PV as B-operand via quad-permutation (__shfl), NO LDS in the loop.
// O^T = V^T*P^T accumulated in C-layout (col=q). Fixed softmax shift exp2(s*c-32):
// partials combine by pure addition. Only the epilogue combine uses LDS + 1 barrier.
// kvh = blk&7 keeps one kv-head per XCD (L2 affinity); longest q-tiles first.
__global__ __launch_bounds__(128, 3) void attn_kernel(const u16* __restrict__ qkv,
                                                      const u16* __restrict__ vt,
                                                      u16* __restrict__ attn_out) {
  __shared__ __align__(16) float Ex[32 * 132];   // [q:32][d:128 +pad] + col128 = lsum
  const int blk = blockIdx.x;
  const int kvh = blk & 7;             // XCD affinity: one kv-head per XCD
  const int hg = (blk >> 3) & 3;
  const int it = 63 - (blk >> 5);      // longest q-tiles dispatched first
  const int h  = kvh * 4 + hg;
  const int tid = threadIdx.x;
  const int wave = tid >> 6, lane = tid & 63;
  const int quad = lane >> 4, l16 = lane & 15;
  const int q0 = it * 32;

  const float c = 0.08838834764831845f * 1.4426950408889634f; // D^-0.5 * log2e

  // Q B-fragments: n=q(l16), k=d(quad*8+j); 2 m-tiles x 4 d-chunks
  bf16x8 qf[2][4];
#pragma unroll
  for (int m = 0; m < 2; m++)
#pragma unroll
    for (int dc = 0; dc < 4; dc++)
      qf[m][dc] = *(const bf16x8*)(qkv + (size_t)(q0 + m * 16 + l16) * QKV_N + h * HD + dc * 32 + quad * 8);

  // K A-fragment pointers: m=key(st*16+l16), k=d; start at this wave's first tile
  const u16* kp[4];
#pragma unroll
  for (int st = 0; st < 4; st++)
    kp[st] = qkv + (size_t)(wave * 64 + st * 16 + l16) * QKV_N + HIDDEN + kvh * HD + quad * 8;
  // V^T A-fragment pointers: m=d(dt*16+l16), k=key
  const u16* vp[8];
#pragma unroll
  for (int dt = 0; dt < 8; dt++)
    vp[dt] = vt + (size_t)(kvh * HD + dt * 16 + l16) * SEQ + wave * 64 + quad * 8;

  float lsum[2] = {0.f, 0.f};
  f32x4 o[2][8] = {};

  const int srcA = ((lane >> 4) & 1) * 32 + l16;   // quad 0 or 2, same l16
  const int srcB = srcA + 16;                      // quad 1 or 3
  const bool hi = quad >= 2;

  const int n_kt = (q0 + 95) >> 6;   // 64-key tiles covering 0 .. q0+31
  for (int kt = wave; kt < n_kt; kt += 2) {
    const bool last = (kt == n_kt - 1);

    // ---- S^T = K Q^T over 64 keys; softmax + pack to bf16 pairs ----
    u32 pk[2][4][2];
#pragma unroll
    for (int st = 0; st < 4; st++) {
      bf16x8 kst[4];
#pragma unroll
      for (int dc = 0; dc < 4; dc++) kst[dc] = *(const bf16x8*)(kp[st] + dc * 32);
      f32x4 s[2] = {};
#pragma unroll
      for (int dc = 0; dc < 4; dc++)
#pragma unroll
        for (int m = 0; m < 2; m++)
          s[m] = __builtin_amdgcn_mfma_f32_16x16x32_bf16(kst[dc], qf[m][dc], s[m], 0, 0, 0);
#pragma unroll
      for (int m = 0; m < 2; m++) {
        float pr[4];
#pragma unroll
        for (int r = 0; r < 4; r++) {
          float v = fmaf(s[m][r], c, -32.0f);
          if (last) {
            int key = kt * 64 + st * 16 + quad * 4 + r;
            if (key > q0 + m * 16 + l16) v = -1e30f;
          }
          pr[r] = exp2f(v);
          lsum[m] += pr[r];
        }
        pk[m][st][0] = ((u32)f2bf(pr[1]) << 16) | f2bf(pr[0]);
        pk[m][st][1] = ((u32)f2bf(pr[3]) << 16) | f2bf(pr[2]);
      }
    }

    // ---- P^T B-fragments via quad permutation (no LDS) ----
    bf16x8 pf[2][2];
#pragma unroll
    for (int m = 0; m < 2; m++)
#pragma unroll
      for (int kc = 0; kc < 2; kc++) {
        union { u32 w[4]; bf16x8 v; } u;
        u32 a0 = (u32)__shfl((int)pk[m][2 * kc][0],     srcA);
        u32 b0 = (u32)__shfl((int)pk[m][2 * kc + 1][0], srcA);
        u32 a1 = (u32)__shfl((int)pk[m][2 * kc][1],     srcA);
        u32 b1 = (u32)__shfl((int)pk[m][2 * kc + 1][1], srcA);
        u32 a2 = (u32)__shfl((int)pk[m][2 * kc][0],     srcB);
        u32 b2 = (u32)__shfl((int)pk[m][2 * kc + 1][0], srcB);
        u32 a3 = (u32)__shfl((int)pk[m][2 * kc][1],     srcB);
        u32 b3 = (u32)__shfl((int)pk[m][2 * kc + 1][1], srcB);
        u.w[0] = hi ? b0 : a0;
        u.w[1] = hi ? b1 : a1;
        u.w[2] = hi ? b2 : a2;
        u.w[3] = hi ? b3 : a3;
        pf[m][kc] = u.v;
      }

    // ---- O^T += V^T P^T ----
#pragma unroll
    for (int dt = 0; dt < 8; dt++) {
      bf16x8 vf0 = *(const bf16x8*)(vp[dt]);
      bf16x8 vf1 = *(const bf16x8*)(vp[dt] + 32);
#pragma unroll
      for (int m = 0; m < 2; m++) {
        o[m][dt] = __builtin_amdgcn_mfma_f32_16x16x32_bf16(vf0, pf[m][0], o[m][dt], 0, 0, 0);
        o[m][dt] = __builtin_amdgcn_mfma_f32_16x16x32_bf16(vf1, pf[m][1], o[m][dt], 0, 0, 0);
      }
    }

#pragma unroll
    for (int st = 0; st < 4; st++) kp[st] += (size_t)128 * QKV_N;   // skip 2 tiles
#pragma unroll
    for (int dt = 0; dt < 8; dt++) vp[dt] += 128;
  }

  // ---- reduce lsum across the 4 quads (q is per-lane l16) ----
#pragma unroll
  for (int m = 0; m < 2; m++) {
    lsum[m] += __shfl_xor(lsum[m], 16);
    lsum[m] += __shfl_xor(lsum[m], 32);
  }

  // ---- combine the two waves' partials (pure addition; fixed shift) ----
  if (wave == 1) {
#pragma unroll
    for (int m = 0; m < 2; m++) {
#pragma unroll
      for (int dt = 0; dt < 8; dt++)
        *(f32x4*)&Ex[(m * 16 + l16) * 132 + dt * 16 + quad * 4] = o[m][dt];
      if (lane < 16) Ex[(m * 16 + l16) * 132 + 128] = lsum[m];
    }
  }
  __syncthreads();
  if (wave == 0) {
#pragma unroll
    for (int m = 0; m < 2; m++) {
      float lt = lsum[m] + Ex[(m * 16 + l16) * 132 + 128];
      float inv = 1.0f / lt;
      size_t base = (size_t)(q0 + m * 16 + l16) * HIDDEN + h * HD;
#pragma unroll
      for (int dt = 0; dt < 8; dt++) {
        f32x4 p = *(const f32x4*)&Ex[(m * 16 + l16) * 132 + dt * 16 + quad * 4];
        float v0 = (o[m][dt][0] + p[0]) * inv;
        float v1 = (o[m][dt][1] + p[1]) * inv;
        float v2 = (o[m][dt][2] + p[2]) * inv;
        float v3 = (o[m][dt][3] + p[3]) * inv;
        u32 w0 = ((u32)f2bf(v1) << 16) | f2bf(v0);
        u32 w1 = ((u32)f2bf(v3) << 16) | f2bf(v2);
        uint2 wv; wv.x = w0; wv.y = w1;
        *(uint2*)&attn_out[base + dt * 16 + quad * 4] = wv;
      }
    }
  }
}

// ---------------- launch ----------------
extern "C" void kernel_launch(void* const* d_in, const int* in_sizes, int n_in,
                              void* d_out, int out_size, void* d_ws, size_t ws_size,
                              hipStream_t stream) {
  const float* x  = (const float*)d_in[0];
  const int* pos  = (const int*)d_in[1];
  const float* Wq = (const float*)d_in[3];
  const float* Wk = (const float*)d_in[4];
  const float* Wv = (const float*)d_in[5];
  const float* Wo = (const float*)d_in[6];
  float* out = (float*)d_out;

  u16* x_bf    = (u16*)d_ws;                                  // 2048*4096
  u16* Wqkv_bf = x_bf + (size_t)SEQ * HIDDEN;                 // 6144*4096
  u16* qkv_bf  = Wqkv_bf + (size_t)QKV_N * HIDDEN;            // 2048*6144
  u16* attn_bf = qkv_bf + (size_t)SEQ * QKV_N;                // 2048*4096
  u16* Wo_bf   = attn_bf + (size_t)SEQ * HIDDEN;              // 4096*4096
  u16* vt_bf   = x_bf;   // reuse x_bf region (dead after gemm1); 1024*2048 fits

  auto cvt = [&](const float* s, u16* d, size_t n) {
    int n8 = (int)(n / 8);
    cvt_f32_bf16<<<(n8 + 255) / 256, 256, 0, stream>>>(s, d, n8);
  };
  cvt(x,  x_bf,    (size_t)SEQ * HIDDEN);
  cvt(Wq, Wqkv_bf,                         (size_t)4096 * 4096);
  cvt(Wk, Wqkv_bf + (size_t)4096 * 4096,   (size_t)1024 * 4096);
  cvt(Wv, Wqkv_bf + (size_t)5120 * 4096,   (size_t)1024 * 4096);
  cvt(Wo, Wo_bf,   (size_t)4096 * 4096);

  // GEMM1: 2048x6144x4096, tile 256x192 -> 8*32 = 256 blocks (full chip, no tail)
  gemm8p<0, 3><<<dim3(256), 512, 0, stream>>>(x_bf, Wqkv_bf, qkv_bf, SEQ, QKV_N, HIDDEN);

  int rope_threads = SEQ * 40 * 64;
  rope_kernel<<<rope_threads / 256, 256, 0, stream>>>(qkv_bf, pos);

  dim3 gt(SEQ / 64, 1024 / 64);
  transpose_v<<<gt, 256, 0, stream>>>(qkv_bf, vt_bf);

  attn_kernel<<<2048, 128, 0, stream>>>(qkv_bf, vt_bf, attn_bf);

  // GEMM3: 2048x4096x4096, tile 256x128 -> 8*32 = 256 blocks (ring-3, 2 blocks/CU)
  gemm8p<1, 2><<<dim3(256), 512, 0, stream>>>(attn_bf, Wo_bf, out, SEQ, HIDDEN, HIDDEN);
}

// Round 3
// 617.890 us; speedup vs baseline: 1.1332x; 1.0194x over previous
//
#include <hip/hip_runtime.h>
#include <hip/hip_bf16.h>
#include <math.h>

#define SEQ    2048
#define HIDDEN 4096
#define NH     32
#define NKV    8
#define HD     128
#define QKV_N  6144   // 4096 q + 1024 k + 1024 v

typedef __attribute__((ext_vector_type(8))) short bf16x8;
typedef __attribute__((ext_vector_type(4))) float f32x4;
typedef unsigned short u16;
typedef unsigned int u32;

#define VMCNT(n) asm volatile("s_waitcnt vmcnt(" #n ")" ::: "memory")
#define LGKM0 do { asm volatile("s_waitcnt lgkmcnt(0)" ::: "memory"); \
                   __builtin_amdgcn_sched_barrier(0); } while (0)

__device__ inline void gl_lds16(const void* g, void* lds) {
  __builtin_amdgcn_global_load_lds((const __attribute__((address_space(1))) void*)g,
                                   (__attribute__((address_space(3))) void*)lds, 16, 0, 0);
}

__device__ inline void tile_bar() {
  __builtin_amdgcn_sched_barrier(0);
  __builtin_amdgcn_s_barrier();
  __builtin_amdgcn_sched_barrier(0);
}

__device__ inline u16 f2bf(float f) {
  __hip_bfloat16 h = __float2bfloat16(f);
  return *(u16*)&h;
}
__device__ inline float bf2f(u16 u) {
  __hip_bfloat16 h = *(__hip_bfloat16*)&u;
  return __bfloat162float(h);
}

// ---------------- fp32 -> bf16 conversion (8 elements / thread) ----------------
__global__ void cvt_f32_bf16(const float* __restrict__ src, u16* __restrict__ dst, int n8) {
  int i = blockIdx.x * blockDim.x + threadIdx.x;
  if (i >= n8) return;
  const float4* s = (const float4*)src + (size_t)i * 2;
  float4 a = s[0], b = s[1];
  float v[8] = {a.x, a.y, a.z, a.w, b.x, b.y, b.z, b.w};
  union { u16 o[8]; uint4 u; } pk;
#pragma unroll
  for (int j = 0; j < 8; j++) pk.o[j] = f2bf(v[j]);
  *(uint4*)(dst + (size_t)i * 8) = pk.u;
}

// ---------------- bf16 GEMM, C = A * B^T  (A: MxK, B: NxK, both row-major) -----------------
// Ring-buffered, two-fine-phase per K-tile schedule (unchanged from R2 — see comments there).
template <int OUTF32, int NF>
__global__ __launch_bounds__(512, NF == 2 ? 4 : 2)
void gemm8p(const u16* __restrict__ A, const u16* __restrict__ B,
            void* __restrict__ Cout, int M, int N, int K) {
  constexpr int RING  = (NF == 2) ? 3 : 4;
  constexpr int BROWS = (NF == 2) ? 128 : 256;
  constexpr int A_ELE = 256 * 32;
  constexpr int B_ELE = BROWS * 32;
  __shared__ __align__(16) u16 Ab[RING * A_ELE];
  __shared__ __align__(16) u16 Bb[RING * B_ELE];

  const int tid = threadIdx.x;
  const int w = tid >> 6, lane = tid & 63;
  const int quad = lane >> 4, l16 = lane & 15;
  const int wm = w >> 2, wn = w & 3;
  constexpr int BN = NF * 64;

  const int bid = blockIdx.x;
  const int nbn = N / BN;
  const int npx = nbn >> 3;
  const int n_idx = (bid & 7) * npx + ((bid >> 3) % npx);
  const int m_idx = bid / (8 * npx);
  const int m0 = m_idx * 256, n0 = n_idx * BN;

  const u16* aS = A + (size_t)(m0 + w * 16 + (lane >> 2)) * K + (lane & 3) * 8;
  const u16* bS = B + (size_t)(n0 + w * 16 + (lane >> 2)) * K + (lane & 3) * 8;
  const size_t boff2 = (size_t)((NF == 3 && w >= 4) ? 0 : 128) * K;

  const int NT = K >> 5;

  f32x4 acc[8][NF] = {};

  auto stageA = [&](int t) {
    const int b = t % RING;
    gl_lds16(aS + (size_t)t * 32, &Ab[b * A_ELE + (w * 16) * 32]);
    gl_lds16(aS + (size_t)128 * K + (size_t)t * 32, &Ab[b * A_ELE + (128 + w * 16) * 32]);
  };
  auto stageB = [&](int t) {
    const int b = t % RING;
    gl_lds16(bS + (size_t)t * 32, &Bb[b * B_ELE + (w * 16) * 32]);
    if constexpr (NF == 3)
      gl_lds16(bS + boff2 + (size_t)t * 32, &Bb[b * B_ELE + (128 + w * 16) * 32]);
    if constexpr (NF == 4)
      gl_lds16(bS + (size_t)128 * K + (size_t)t * 32, &Bb[b * B_ELE + (128 + w * 16) * 32]);
  };

  if constexpr (NF == 2) {
    stageA(0); stageB(0); stageA(1); stageB(1);
    VMCNT(3);
  } else {
    stageA(0); stageB(0); stageA(1); stageB(1); stageA(2); stageB(2);
    VMCNT(8);
  }
  tile_bar();

  for (int t = 0; t < NT; ++t) {
    const int b = t % RING;
    const u16* Abt = &Ab[b * A_ELE];
    const u16* Bbt = &Bb[b * B_ELE];

    bf16x8 af0[4], bfv[NF];
#pragma unroll
    for (int f = 0; f < 4; ++f)
      af0[f] = *(const bf16x8*)&Abt[(wm * 128 + f * 16 + l16) * 32 + quad * 8];
#pragma unroll
    for (int n = 0; n < NF; ++n)
      bfv[n] = *(const bf16x8*)&Bbt[(wn * (NF * 16) + n * 16 + l16) * 32 + quad * 8];
    if (t + RING - 1 < NT) stageA(t + RING - 1);
    tile_bar();
    LGKM0;
    __builtin_amdgcn_s_setprio(1);
#pragma unroll
    for (int f = 0; f < 4; ++f)
#pragma unroll
      for (int n = 0; n < NF; ++n)
        acc[f][n] = __builtin_amdgcn_mfma_f32_16x16x32_bf16(af0[f], bfv[n], acc[f][n], 0, 0, 0);
    __builtin_amdgcn_s_setprio(0);
    tile_bar();

    bf16x8 af1[4];
#pragma unroll
    for (int f = 0; f < 4; ++f)
      af1[f] = *(const bf16x8*)&Abt[(wm * 128 + (4 + f) * 16 + l16) * 32 + quad * 8];
    if (t + RING - 1 < NT) stageB(t + RING - 1);
    tile_bar();
    LGKM0;
    __builtin_amdgcn_s_setprio(1);
#pragma unroll
    for (int f = 0; f < 4; ++f)
#pragma unroll
      for (int n = 0; n < NF; ++n)
        acc[4 + f][n] = __builtin_amdgcn_mfma_f32_16x16x32_bf16(af1[f], bfv[n], acc[4 + f][n], 0, 0, 0);
    __builtin_amdgcn_s_setprio(0);

    if (t < NT - 1) {
      if constexpr (NF == 2) {
        if (t + 2 < NT) { VMCNT(3); } else { VMCNT(0); }
      } else {
        if (t + 3 < NT)       { VMCNT(8); }
        else if (t + 3 == NT) { VMCNT(4); }
        else                  { VMCNT(0); }
      }
      tile_bar();
    }
  }

#pragma unroll
  for (int f = 0; f < 8; ++f)
#pragma unroll
    for (int n = 0; n < NF; ++n)
#pragma unroll
      for (int r = 0; r < 4; ++r) {
        int row = m0 + wm * 128 + f * 16 + quad * 4 + r;
        int col = n0 + wn * (NF * 16) + n * 16 + l16;
        float v = acc[f][n][r];
        if (OUTF32) ((float*)Cout)[(size_t)row * N + col] = v;
        else        ((u16*)Cout)[(size_t)row * N + col] = f2bf(v);
      }
}

// ---------------- RoPE in-place on bf16 qkv buffer (q heads 0..31, k heads 0..7) ------------
__global__ void rope_kernel(u16* __restrict__ qkv, const int* __restrict__ pos_ids) {
  int idx = blockIdx.x * blockDim.x + threadIdx.x;
  int d = idx & 63;
  int h = (idx >> 6) % 40;
  int s = idx / (64 * 40);
  if (s >= SEQ) return;
  int off = (h < NH) ? h * HD : HIDDEN + (h - NH) * HD;
  u16* base = qkv + (size_t)s * QKV_N + off;
  float inv_freq = powf(10000.0f, -(float)d * (1.0f / 64.0f));
  float ang = (float)pos_ids[s] * inv_freq;
  float sn, cs;
  sincosf(ang, &sn, &cs);
  float x1 = bf2f(base[d]);
  float x2 = bf2f(base[d + 64]);
  base[d]      = f2bf(x1 * cs - x2 * sn);
  base[d + 64] = f2bf(x2 * cs + x1 * sn);
}

// ---------------- V transpose: qkv v-slice [s][c] -> vt[c][s]  (c = kvh*128+d, 1024 x 2048) --
__global__ __launch_bounds__(256) void transpose_v(const u16* __restrict__ qkv,
                                                   u16* __restrict__ vt) {
  __shared__ u16 t[64][72];
  const int s0 = blockIdx.x * 64, c0 = blockIdx.y * 64;
  const int tid = threadIdx.x;
#pragma unroll
  for (int i = 0; i < 2; i++) {
    int r = (tid >> 3) + i * 32;
    int c = (tid & 7) * 8;
    *(uint4*)&t[r][c] = *(const uint4*)&qkv[(size_t)(s0 + r) * QKV_N + 5120 + c0 + c];
  }
  __syncthreads();
#pragma unroll
  for (int i = 0; i < 2; i++) {
    int c = (tid >> 3) + i * 32;
    int s = (tid & 7) * 8;
    union { uint4 u; u16 e[8]; } o;
#pragma unroll
    for (int j = 0; j < 8; j++) o.e[j] = t[s + j][c];
    *(uint4*)&vt[(size_t)(c0 + c) * SEQ + s0 + s] = o.u;
  }
}

// ---------------- flash attention v6: v5 + deep in-register pipelining ----------------------
// Same math/layout/grid as v5 (S^T form, shuffle P transform, 2-wave split-K, fixed shift).
// New: (1) K st-group double-buffer prefetch (st+1 issued during st's MFMA+softmax; at st=3
//      the NEXT tile's st0 is issued -> full softmax+shfl+PV phase of latency cover),
//      (2) all 16 V fragments issued into registers before/during the shuffle phase so PV
//      never waits on L2, (3) setprio around MFMA clusters, (4) launch_bounds(128,2) to give
//      the ~230-reg live set room (old ",3" would spill). Occupancy band (129-256 regs,
//      8 waves/CU) is unchanged -> the extra registers are free; the win is pure ILP.
__global__ __launch_bounds__(128, 2) void attn_kernel(const u16* __restrict__ qkv,
                                                      const u16* __restrict__ vt,
                                                      u16* __restrict__ attn_out) {
  __shared__ __align__(16) float Ex[32 * 132];   // [q:32][d:128 +pad] + col128 = lsum
  const int blk = blockIdx.x;
  const int kvh = blk & 7;             // XCD affinity: one kv-head per XCD
  const int hg = (blk >> 3) & 3;
  const int it = 63 - (blk >> 5);      // longest q-tiles dispatched first
  const int h  = kvh * 4 + hg;
  const int tid = threadIdx.x;
  const int wave = tid >> 6, lane = tid & 63;
  const int quad = lane >> 4, l16 = lane & 15;
  const int q0 = it * 32;

  const float c = 0.08838834764831845f * 1.4426950408889634f; // D^-0.5 * log2e

  // Q B-fragments: n=q(l16), k=d(quad*8+j); 2 m-tiles x 4 d-chunks
  bf16x8 qf[2][4];
#pragma unroll
  for (int m = 0; m < 2; m++)
#pragma unroll
    for (int dc = 0; dc < 4; dc++)
      qf[m][dc] = *(const bf16x8*)(qkv + (size_t)(q0 + m * 16 + l16) * QKV_N + h * HD + dc * 32 + quad * 8);

  // K A-fragment pointers: m=key(st*16+l16), k=d; start at this wave's first tile
  const u16* kp[4];
#pragma unroll
  for (int st = 0; st < 4; st++)
    kp[st] = qkv + (size_t)(wave * 64 + st * 16 + l16) * QKV_N + HIDDEN + kvh * HD + quad * 8;
  // V^T A-fragment pointers: m=d(dt*16+l16), k=key
  const u16* vp[8];
#pragma unroll
  for (int dt = 0; dt < 8; dt++)
    vp[dt] = vt + (size_t)(kvh * HD + dt * 16 + l16) * SEQ + wave * 64 + quad * 8;

  float lsum[2] = {0.f, 0.f};
  f32x4 o[2][8] = {};

  const int srcA = ((lane >> 4) & 1) * 32 + l16;   // quad 0 or 2, same l16
  const int srcB = srcA + 16;                      // quad 1 or 3
  const bool hi = quad >= 2;

  const int n_kt = (q0 + 95) >> 6;   // 64-key tiles covering 0 .. q0+31

  // preload st0 K-fragments of this wave's first tile (rows < 128: always valid memory)
  bf16x8 kbuf[2][4];
#pragma unroll
  for (int dc = 0; dc < 4; dc++) kbuf[0][dc] = *(const bf16x8*)(kp[0] + dc * 32);

  for (int kt = wave; kt < n_kt; kt += 2) {
    const bool last = (kt == n_kt - 1);

    // ---- S^T = K Q^T over 64 keys; K double-buffer prefetch; softmax; pack bf16 pairs ----
    u32 pk[2][4][2];
#pragma unroll
    for (int st = 0; st < 4; st++) {
      const int cb = st & 1;
      // prefetch next st-group (or st0 of this wave's next tile; tail overrun stays in ws)
      const u16* np = (st < 3) ? kp[st + 1] : kp[0] + (size_t)128 * QKV_N;
#pragma unroll
      for (int dc = 0; dc < 4; dc++) kbuf[cb ^ 1][dc] = *(const bf16x8*)(np + dc * 32);
      __builtin_amdgcn_sched_barrier(0);   // pin prefetch issue before the MFMA cluster

      f32x4 s[2] = {};
      __builtin_amdgcn_s_setprio(1);
#pragma unroll
      for (int dc = 0; dc < 4; dc++)
#pragma unroll
        for (int m = 0; m < 2; m++)
          s[m] = __builtin_amdgcn_mfma_f32_16x16x32_bf16(kbuf[cb][dc], qf[m][dc], s[m], 0, 0, 0);
      __builtin_amdgcn_s_setprio(0);
#pragma unroll
      for (int m = 0; m < 2; m++) {
        float pr[4];
#pragma unroll
        for (int r = 0; r < 4; r++) {
          float v = fmaf(s[m][r], c, -32.0f);
          if (last) {
            int key = kt * 64 + st * 16 + quad * 4 + r;
            if (key > q0 + m * 16 + l16) v = -1e30f;
          }
          pr[r] = exp2f(v);
          lsum[m] += pr[r];
        }
        pk[m][st][0] = ((u32)f2bf(pr[1]) << 16) | f2bf(pr[0]);
        pk[m][st][1] = ((u32)f2bf(pr[3]) << 16) | f2bf(pr[2]);
      }
    }

    // ---- early V issue (lo half), then P^T shuffles m=0 ----
    bf16x8 vbuf[8][2];
#pragma unroll
    for (int dt = 0; dt < 4; dt++) {
      vbuf[dt][0] = *(const bf16x8*)(vp[dt]);
      vbuf[dt][1] = *(const bf16x8*)(vp[dt] + 32);
    }
    __builtin_amdgcn_sched_barrier(0);   // pin V-lo issue before the shuffle phase

    bf16x8 pf[2][2];
#pragma unroll
    for (int m = 0; m < 2; m++) {
      if (m == 1) {
        // ---- early V issue (hi half) between the two shuffle groups ----
#pragma unroll
        for (int dt = 4; dt < 8; dt++) {
          vbuf[dt][0] = *(const bf16x8*)(vp[dt]);
          vbuf[dt][1] = *(const bf16x8*)(vp[dt] + 32);
        }
        __builtin_amdgcn_sched_barrier(0);
      }
#pragma unroll
      for (int kc = 0; kc < 2; kc++) {
        union { u32 w[4]; bf16x8 v; } u;
        u32 a0 = (u32)__shfl((int)pk[m][2 * kc][0],     srcA);
        u32 b0 = (u32)__shfl((int)pk[m][2 * kc + 1][0], srcA);
        u32 a1 = (u32)__shfl((int)pk[m][2 * kc][1],     srcA);
        u32 b1 = (u32)__shfl((int)pk[m][2 * kc + 1][1], srcA);
        u32 a2 = (u32)__shfl((int)pk[m][2 * kc][0],     srcB);
        u32 b2 = (u32)__shfl((int)pk[m][2 * kc + 1][0], srcB);
        u32 a3 = (u32)__shfl((int)pk[m][2 * kc][1],     srcB);
        u32 b3 = (u32)__shfl((int)pk[m][2 * kc + 1][1], srcB);
        u.w[0] = hi ? b0 : a0;
        u.w[1] = hi ? b1 : a1;
        u.w[2] = hi ? b2 : a2;
        u.w[3] = hi ? b3 : a3;
        pf[m][kc] = u.v;
      }
    }

    // ---- O^T += V^T P^T (V already in registers) ----
    __builtin_amdgcn_s_setprio(1);
#pragma unroll
    for (int dt = 0; dt < 8; dt++) {
#pragma unroll
      for (int m = 0; m < 2; m++) {
        o[m][dt] = __builtin_amdgcn_mfma_f32_16x16x32_bf16(vbuf[dt][0], pf[m][0], o[m][dt], 0, 0, 0);
        o[m][dt] = __builtin_amdgcn_mfma_f32_16x16x32_bf16(vbuf[dt][1], pf[m][1], o[m][dt], 0, 0, 0);
      }
    }
    __builtin_amdgcn_s_setprio(0);

#pragma unroll
    for (int st = 0; st < 4; st++) kp[st] += (size_t)128 * QKV_N;   // skip 2 tiles
#pragma unroll
    for (int dt = 0; dt < 8; dt++) vp[dt] += 128;
  }

  // ---- reduce lsum across the 4 quads (q is per-lane l16) ----
#pragma unroll
  for (int m = 0; m < 2; m++) {
    lsum[m] += __shfl_xor(lsum[m], 16);
    lsum[m] += __shfl_xor(lsum[m], 32);
  }

  // ---- combine the two waves' partials (pure addition; fixed shift) ----
  if (wave == 1) {
#pragma unroll
    for (int m = 0; m < 2; m++) {
#pragma unroll
      for (int dt = 0; dt < 8; dt++)
        *(f32x4*)&Ex[(m * 16 + l16) * 132 + dt * 16 + quad * 4] = o[m][dt];
      if (lane < 16) Ex[(m * 16 + l16) * 132 + 128] = lsum[m];
    }
  }
  __syncthreads();
  if (wave == 0) {
#pragma unroll
    for (int m = 0; m < 2; m++) {
      float lt = lsum[m] + Ex[(m * 16 + l16) * 132 + 128];
      float inv = 1.0f / lt;
      size_t base = (size_t)(q0 + m * 16 + l16) * HIDDEN + h * HD;
#pragma unroll
      for (int dt = 0; dt < 8; dt++) {
        f32x4 p = *(const f32x4*)&Ex[(m * 16 + l16) * 132 + dt * 16 + quad * 4];
        float v0 = (o[m][dt][0] + p[0]) * inv;
        float v1 = (o[m][dt][1] + p[1]) * inv;
        float v2 = (o[m][dt][2] + p[2]) * inv;
        float v3 = (o[m][dt][3] + p[3]) * inv;
        u32 w0 = ((u32)f2bf(v1) << 16) | f2bf(v0);
        u32 w1 = ((u32)f2bf(v3) << 16) | f2bf(v2);
        uint2 wv; wv.x = w0; wv.y = w1;
        *(uint2*)&attn_out[base + dt * 16 + quad * 4] = wv;
      }
    }
  }
}

// ---------------- launch ----------------
extern "C" void kernel_launch(void* const* d_in, const int* in_sizes, int n_in,
                              void* d_out, int out_size, void* d_ws, size_t ws_size,
                              hipStream_t stream) {
  const float* x  = (const float*)d_in[0];
  const int* pos  = (const int*)d_in[1];
  const float* Wq = (const float*)d_in[3];
  const float* Wk = (const float*)d_in[4];
  const float* Wv = (const float*)d_in[5];
  const float* Wo = (const float*)d_in[6];
  float* out = (float*)d_out;

  u16* x_bf    = (u16*)d_ws;                                  // 2048*4096
  u16* Wqkv_bf = x_bf + (size_t)SEQ * HIDDEN;                 // 6144*4096
  u16* qkv_bf  = Wqkv_bf + (size_t)QKV_N * HIDDEN;            // 2048*6144
  u16* attn_bf = qkv_bf + (size_t)SEQ * QKV_N;                // 2048*4096
  u16* Wo_bf   = attn_bf + (size_t)SEQ * HIDDEN;              // 4096*4096
  u16* vt_bf   = x_bf;   // reuse x_bf region (dead after gemm1); 1024*2048 fits

  auto cvt = [&](const float* s, u16* d, size_t n) {
    int n8 = (int)(n / 8);
    cvt_f32_bf16<<<(n8 + 255) / 256, 256, 0, stream>>>(s, d, n8);
  };
  cvt(x,  x_bf,    (size_t)SEQ * HIDDEN);
  cvt(Wq, Wqkv_bf,                         (size_t)4096 * 4096);
  cvt(Wk, Wqkv_bf + (size_t)4096 * 4096,   (size_t)1024 * 4096);
  cvt(Wv, Wqkv_bf + (size_t)5120 * 4096,   (size_t)1024 * 4096);
  cvt(Wo, Wo_bf,   (size_t)4096 * 4096);

  // GEMM1: 2048x6144x4096, tile 256x192 -> 8*32 = 256 blocks (full chip, no tail)
  gemm8p<0, 3><<<dim3(256), 512, 0, stream>>>(x_bf, Wqkv_bf, qkv_bf, SEQ, QKV_N, HIDDEN);

  int rope_threads = SEQ * 40 * 64;
  rope_kernel<<<rope_threads / 256, 256, 0, stream>>>(qkv_bf, pos);

  dim3 gt(SEQ / 64, 1024 / 64);
  transpose_v<<<gt, 256, 0, stream>>>(qkv_bf, vt_bf);

  attn_kernel<<<2048, 128, 0, stream>>>(qkv_bf, vt_bf, attn_bf);

  // GEMM3: 2048x4096x4096, tile 256x128 -> 8*32 = 256 blocks (ring-3, 2 blocks/CU)
  gemm8p<1, 2><<<dim3(256), 512, 0, stream>>>(attn_bf, Wo_bf, out, SEQ, HIDDEN, HIDDEN);
}

// Round 4
// 579.633 us; speedup vs baseline: 1.2080x; 1.0660x over previous
//
#include <hip/hip_runtime.h>
#include <hip/hip_bf16.h>
#include <math.h>

#define SEQ    2048
#define HIDDEN 4096
#define NH     32
#define NKV    8
#define HD     128
#define QKV_N  6144   // 4096 q + 1024 k + 1024 v

typedef __attribute__((ext_vector_type(8))) short bf16x8;
typedef __attribute__((ext_vector_type(4))) float f32x4;
typedef unsigned short u16;
typedef unsigned int u32;

#define VMCNT(n) asm volatile("s_waitcnt vmcnt(" #n ")" ::: "memory")
#define LGKMW(n) do { asm volatile("s_waitcnt lgkmcnt(" #n ")" ::: "memory"); \
                      __builtin_amdgcn_sched_barrier(0); } while (0)

__device__ inline void gl_lds16(const void* g, void* lds) {
  __builtin_amdgcn_global_load_lds((const __attribute__((address_space(1))) void*)g,
                                   (__attribute__((address_space(3))) void*)lds, 16, 0, 0);
}

__device__ inline void tile_bar() {
  __builtin_amdgcn_sched_barrier(0);
  __builtin_amdgcn_s_barrier();
  __builtin_amdgcn_sched_barrier(0);
}

__device__ inline u16 f2bf(float f) {
  __hip_bfloat16 h = __float2bfloat16(f);
  return *(u16*)&h;
}
__device__ inline float bf2f(u16 u) {
  __hip_bfloat16 h = *(__hip_bfloat16*)&u;
  return __bfloat162float(h);
}

// ---------------- fp32 -> bf16 conversion (8 elements / thread) ----------------
__global__ void cvt_f32_bf16(const float* __restrict__ src, u16* __restrict__ dst, int n8) {
  int i = blockIdx.x * blockDim.x + threadIdx.x;
  if (i >= n8) return;
  const float4* s = (const float4*)src + (size_t)i * 2;
  float4 a = s[0], b = s[1];
  float v[8] = {a.x, a.y, a.z, a.w, b.x, b.y, b.z, b.w};
  union { u16 o[8]; uint4 u; } pk;
#pragma unroll
  for (int j = 0; j < 8; j++) pk.o[j] = f2bf(v[j]);
  *(uint4*)(dst + (size_t)i * 8) = pk.u;
}

// ---------------- bf16 GEMM, C = A * B^T  (A: MxK, B: NxK, both row-major) -----------------
// Ring-4, ONE barrier per K-tile, counted-lgkm overlap:
//   block = (MF*32) x (NF*64), BK=32, 8 waves (2M x 4N), 512 threads; wave tile MF*16 x NF*16.
//   Per tile: [issue bfv(NF)+af(MF) ds_reads] [stage tile t+3] lgkmcnt(MF/2) -> cluster1 MFMA
//   (af first half x bfv, runs while remaining ds_reads are served) -> lgkmcnt(0) -> cluster2
//   -> counted vmcnt -> s_barrier. Reads stay outstanding under MFMAs (the m201 mechanism);
//   waves desync within the tile window so LDS serving pipelines against MFMA issue.
//   Hazards: stage(t+3) writes buf[(t-1)%4], whose reads completed before the prior barrier
//   (lgkm0 precedes it); vmcnt before the barrier => tile t+1 landed chip-wide after it.
//   GEMM1: MF=8,NF=3 (256x192, grid 256, B rows padded via w>=4 dup).
//   GEMM3: MF=4,NF=4 (128x256, grid 256, exact fit).
template <int OUTF32, int MF, int NF>
__global__ __launch_bounds__(512, 2)
void gemm8p(const u16* __restrict__ A, const u16* __restrict__ B,
            void* __restrict__ Cout, int M, int N, int K) {
  constexpr int RING   = 4;
  constexpr int A_ROWS = MF * 32;                       // 2 wm * MF * 16
  constexpr int B_LOG  = NF * 64;                       // logical B rows (BN)
  constexpr int B_ROWS = (NF == 3) ? 256 : B_LOG;       // physical (NF=3 pads)
  constexpr int A_ELE  = A_ROWS * 32;
  constexpr int B_ELE  = B_ROWS * 32;
  __shared__ __align__(16) u16 Ab[RING * A_ELE];
  __shared__ __align__(16) u16 Bb[RING * B_ELE];

  const int tid = threadIdx.x;
  const int w = tid >> 6, lane = tid & 63;
  const int quad = lane >> 4, l16 = lane & 15;
  const int wm = w >> 2, wn = w & 3;
  constexpr int BN = B_LOG;

  // XCD mapping: bid&7 = XCD; each XCD owns contiguous n-panels (B slice L2-resident)
  const int bid = blockIdx.x;
  const int nbn = N / BN;
  const int npx = nbn >> 3;
  const int n_idx = (bid & 7) * npx + ((bid >> 3) % npx);
  const int m_idx = bid / (8 * npx);
  const int m0 = m_idx * A_ROWS, n0 = n_idx * BN;

  // staging source: wave covers 16 rows x 32 cols per call; lane l -> row +(l>>2), slot l&3
  const u16* aS = A + (size_t)(m0 + w * 16 + (lane >> 2)) * K + (lane & 3) * 8;
  const u16* bS = B + (size_t)(n0 + w * 16 + (lane >> 2)) * K + (lane & 3) * 8;
  const size_t boff2 = (size_t)((NF == 3 && w >= 4) ? 0 : 128) * K;  // NF=3 pad dup

  const int NT = K >> 5;
  constexpr int LPT = A_ROWS / 128 + B_ROWS / 128;   // gl_lds16 per wave per tile (4 or 3)

  f32x4 acc[MF][NF] = {};

  auto stage = [&](int t) {
    const int b = t % RING;
    const size_t ko = (size_t)t * 32;
    gl_lds16(aS + ko, &Ab[b * A_ELE + (w * 16) * 32]);
    if constexpr (A_ROWS == 256)
      gl_lds16(aS + (size_t)128 * K + ko, &Ab[b * A_ELE + (128 + w * 16) * 32]);
    gl_lds16(bS + ko, &Bb[b * B_ELE + (w * 16) * 32]);
    if constexpr (NF == 3)
      gl_lds16(bS + boff2 + ko, &Bb[b * B_ELE + (128 + w * 16) * 32]);
    else if constexpr (B_ROWS == 256)
      gl_lds16(bS + (size_t)128 * K + ko, &Bb[b * B_ELE + (128 + w * 16) * 32]);
  };

  // prologue: 3 tiles in flight, wait only for tile 0 (= leave 2*LPT outstanding)
  stage(0); stage(1); stage(2);
  if constexpr (LPT == 4) { VMCNT(8); } else { VMCNT(6); }
  tile_bar();

  for (int t = 0; t < NT; ++t) {
    const int b = t % RING;
    const u16* Abt = &Ab[b * A_ELE];
    const u16* Bbt = &Bb[b * B_ELE];

    // ---- issue all fragment reads (bfv first, then af halves), then next stage ----
    bf16x8 bfv[NF], af0[MF / 2], af1[MF / 2];
#pragma unroll
    for (int n = 0; n < NF; ++n)
      bfv[n] = *(const bf16x8*)&Bbt[(wn * (NF * 16) + n * 16 + l16) * 32 + quad * 8];
#pragma unroll
    for (int f = 0; f < MF / 2; ++f)
      af0[f] = *(const bf16x8*)&Abt[(wm * (MF * 16) + f * 16 + l16) * 32 + quad * 8];
#pragma unroll
    for (int f = 0; f < MF / 2; ++f)
      af1[f] = *(const bf16x8*)&Abt[(wm * (MF * 16) + (MF / 2 + f) * 16 + l16) * 32 + quad * 8];
    if (t + 3 < NT) stage(t + 3);

    // ---- cluster 1: needs bfv + af0 (first NF+MF/2 reads); af1 still in flight ----
    if constexpr (MF == 8) { LGKMW(4); } else { LGKMW(2); }
    __builtin_amdgcn_s_setprio(1);
#pragma unroll
    for (int f = 0; f < MF / 2; ++f)
#pragma unroll
      for (int n = 0; n < NF; ++n)
        acc[f][n] = __builtin_amdgcn_mfma_f32_16x16x32_bf16(af0[f], bfv[n], acc[f][n], 0, 0, 0);
    __builtin_amdgcn_s_setprio(0);

    // ---- cluster 2: af1 (completed under cluster 1) ----
    LGKMW(0);
    __builtin_amdgcn_s_setprio(1);
#pragma unroll
    for (int f = 0; f < MF / 2; ++f)
#pragma unroll
      for (int n = 0; n < NF; ++n)
        acc[MF / 2 + f][n] =
            __builtin_amdgcn_mfma_f32_16x16x32_bf16(af1[f], bfv[n], acc[MF / 2 + f][n], 0, 0, 0);
    __builtin_amdgcn_s_setprio(0);

    // ---- tile boundary: counted vmcnt (t+1 landed; t+2,t+3 in flight), ONE barrier ----
    if (t < NT - 1) {
      if constexpr (LPT == 4) {
        if (t + 3 < NT)       { VMCNT(8); }
        else if (t + 3 == NT) { VMCNT(4); }
        else                  { VMCNT(0); }
      } else {
        if (t + 3 < NT)       { VMCNT(6); }
        else if (t + 3 == NT) { VMCNT(3); }
        else                  { VMCNT(0); }
      }
      tile_bar();
    }
  }

#pragma unroll
  for (int f = 0; f < MF; ++f)
#pragma unroll
    for (int n = 0; n < NF; ++n)
#pragma unroll
      for (int r = 0; r < 4; ++r) {
        int row = m0 + wm * (MF * 16) + f * 16 + quad * 4 + r;
        int col = n0 + wn * (NF * 16) + n * 16 + l16;
        float v = acc[f][n][r];
        if (OUTF32) ((float*)Cout)[(size_t)row * N + col] = v;
        else        ((u16*)Cout)[(size_t)row * N + col] = f2bf(v);
      }
}

// ---------------- RoPE in-place on bf16 qkv buffer (q heads 0..31, k heads 0..7) ------------
__global__ void rope_kernel(u16* __restrict__ qkv, const int* __restrict__ pos_ids) {
  int idx = blockIdx.x * blockDim.x + threadIdx.x;
  int d = idx & 63;
  int h = (idx >> 6) % 40;
  int s = idx / (64 * 40);
  if (s >= SEQ) return;
  int off = (h < NH) ? h * HD : HIDDEN + (h - NH) * HD;
  u16* base = qkv + (size_t)s * QKV_N + off;
  float inv_freq = powf(10000.0f, -(float)d * (1.0f / 64.0f));
  float ang = (float)pos_ids[s] * inv_freq;
  float sn, cs;
  sincosf(ang, &sn, &cs);
  float x1 = bf2f(base[d]);
  float x2 = bf2f(base[d + 64]);
  base[d]      = f2bf(x1 * cs - x2 * sn);
  base[d + 64] = f2bf(x2 * cs + x1 * sn);
}

// ---------------- V transpose: qkv v-slice [s][c] -> vt[c][s]  (c = kvh*128+d, 1024 x 2048) --
__global__ __launch_bounds__(256) void transpose_v(const u16* __restrict__ qkv,
                                                   u16* __restrict__ vt) {
  __shared__ u16 t[64][72];
  const int s0 = blockIdx.x * 64, c0 = blockIdx.y * 64;
  const int tid = threadIdx.x;
#pragma unroll
  for (int i = 0; i < 2; i++) {
    int r = (tid >> 3) + i * 32;
    int c = (tid & 7) * 8;
    *(uint4*)&t[r][c] = *(const uint4*)&qkv[(size_t)(s0 + r) * QKV_N + 5120 + c0 + c];
  }
  __syncthreads();
#pragma unroll
  for (int i = 0; i < 2; i++) {
    int c = (tid >> 3) + i * 32;
    int s = (tid & 7) * 8;
    union { uint4 u; u16 e[8]; } o;
#pragma unroll
    for (int j = 0; j < 8; j++) o.e[j] = t[s + j][c];
    *(uint4*)&vt[(size_t)(c0 + c) * SEQ + s0 + s] = o.u;
  }
}

// ---------------- flash attention v6 (unchanged from R3) ------------------------------------
__global__ __launch_bounds__(128, 2) void attn_kernel(const u16* __restrict__ qkv,
                                                      const u16* __restrict__ vt,
                                                      u16* __restrict__ attn_out) {
  __shared__ __align__(16) float Ex[32 * 132];   // [q:32][d:128 +pad] + col128 = lsum
  const int blk = blockIdx.x;
  const int kvh = blk & 7;             // XCD affinity: one kv-head per XCD
  const int hg = (blk >> 3) & 3;
  const int it = 63 - (blk >> 5);      // longest q-tiles dispatched first
  const int h  = kvh * 4 + hg;
  const int tid = threadIdx.x;
  const int wave = tid >> 6, lane = tid & 63;
  const int quad = lane >> 4, l16 = lane & 15;
  const int q0 = it * 32;

  const float c = 0.08838834764831845f * 1.4426950408889634f; // D^-0.5 * log2e

  bf16x8 qf[2][4];
#pragma unroll
  for (int m = 0; m < 2; m++)
#pragma unroll
    for (int dc = 0; dc < 4; dc++)
      qf[m][dc] = *(const bf16x8*)(qkv + (size_t)(q0 + m * 16 + l16) * QKV_N + h * HD + dc * 32 + quad * 8);

  const u16* kp[4];
#pragma unroll
  for (int st = 0; st < 4; st++)
    kp[st] = qkv + (size_t)(wave * 64 + st * 16 + l16) * QKV_N + HIDDEN + kvh * HD + quad * 8;
  const u16* vp[8];
#pragma unroll
  for (int dt = 0; dt < 8; dt++)
    vp[dt] = vt + (size_t)(kvh * HD + dt * 16 + l16) * SEQ + wave * 64 + quad * 8;

  float lsum[2] = {0.f, 0.f};
  f32x4 o[2][8] = {};

  const int srcA = ((lane >> 4) & 1) * 32 + l16;   // quad 0 or 2, same l16
  const int srcB = srcA + 16;                      // quad 1 or 3
  const bool hi = quad >= 2;

  const int n_kt = (q0 + 95) >> 6;   // 64-key tiles covering 0 .. q0+31

  bf16x8 kbuf[2][4];
#pragma unroll
  for (int dc = 0; dc < 4; dc++) kbuf[0][dc] = *(const bf16x8*)(kp[0] + dc * 32);

  for (int kt = wave; kt < n_kt; kt += 2) {
    const bool last = (kt == n_kt - 1);

    u32 pk[2][4][2];
#pragma unroll
    for (int st = 0; st < 4; st++) {
      const int cb = st & 1;
      const u16* np = (st < 3) ? kp[st + 1] : kp[0] + (size_t)128 * QKV_N;
#pragma unroll
      for (int dc = 0; dc < 4; dc++) kbuf[cb ^ 1][dc] = *(const bf16x8*)(np + dc * 32);
      __builtin_amdgcn_sched_barrier(0);

      f32x4 s[2] = {};
      __builtin_amdgcn_s_setprio(1);
#pragma unroll
      for (int dc = 0; dc < 4; dc++)
#pragma unroll
        for (int m = 0; m < 2; m++)
          s[m] = __builtin_amdgcn_mfma_f32_16x16x32_bf16(kbuf[cb][dc], qf[m][dc], s[m], 0, 0, 0);
      __builtin_amdgcn_s_setprio(0);
#pragma unroll
      for (int m = 0; m < 2; m++) {
        float pr[4];
#pragma unroll
        for (int r = 0; r < 4; r++) {
          float v = fmaf(s[m][r], c, -32.0f);
          if (last) {
            int key = kt * 64 + st * 16 + quad * 4 + r;
            if (key > q0 + m * 16 + l16) v = -1e30f;
          }
          pr[r] = exp2f(v);
          lsum[m] += pr[r];
        }
        pk[m][st][0] = ((u32)f2bf(pr[1]) << 16) | f2bf(pr[0]);
        pk[m][st][1] = ((u32)f2bf(pr[3]) << 16) | f2bf(pr[2]);
      }
    }

    bf16x8 vbuf[8][2];
#pragma unroll
    for (int dt = 0; dt < 4; dt++) {
      vbuf[dt][0] = *(const bf16x8*)(vp[dt]);
      vbuf[dt][1] = *(const bf16x8*)(vp[dt] + 32);
    }
    __builtin_amdgcn_sched_barrier(0);

    bf16x8 pf[2][2];
#pragma unroll
    for (int m = 0; m < 2; m++) {
      if (m == 1) {
#pragma unroll
        for (int dt = 4; dt < 8; dt++) {
          vbuf[dt][0] = *(const bf16x8*)(vp[dt]);
          vbuf[dt][1] = *(const bf16x8*)(vp[dt] + 32);
        }
        __builtin_amdgcn_sched_barrier(0);
      }
#pragma unroll
      for (int kc = 0; kc < 2; kc++) {
        union { u32 w[4]; bf16x8 v; } u;
        u32 a0 = (u32)__shfl((int)pk[m][2 * kc][0],     srcA);
        u32 b0 = (u32)__shfl((int)pk[m][2 * kc + 1][0], srcA);
        u32 a1 = (u32)__shfl((int)pk[m][2 * kc][1],     srcA);
        u32 b1 = (u32)__shfl((int)pk[m][2 * kc + 1][1], srcA);
        u32 a2 = (u32)__shfl((int)pk[m][2 * kc][0],     srcB);
        u32 b2 = (u32)__shfl((int)pk[m][2 * kc + 1][0], srcB);
        u32 a3 = (u32)__shfl((int)pk[m][2 * kc][1],     srcB);
        u32 b3 = (u32)__shfl((int)pk[m][2 * kc + 1][1], srcB);
        u.w[0] = hi ? b0 : a0;
        u.w[1] = hi ? b1 : a1;
        u.w[2] = hi ? b2 : a2;
        u.w[3] = hi ? b3 : a3;
        pf[m][kc] = u.v;
      }
    }

    __builtin_amdgcn_s_setprio(1);
#pragma unroll
    for (int dt = 0; dt < 8; dt++) {
#pragma unroll
      for (int m = 0; m < 2; m++) {
        o[m][dt] = __builtin_amdgcn_mfma_f32_16x16x32_bf16(vbuf[dt][0], pf[m][0], o[m][dt], 0, 0, 0);
        o[m][dt] = __builtin_amdgcn_mfma_f32_16x16x32_bf16(vbuf[dt][1], pf[m][1], o[m][dt], 0, 0, 0);
      }
    }
    __builtin_amdgcn_s_setprio(0);

#pragma unroll
    for (int st = 0; st < 4; st++) kp[st] += (size_t)128 * QKV_N;   // skip 2 tiles
#pragma unroll
    for (int dt = 0; dt < 8; dt++) vp[dt] += 128;
  }

#pragma unroll
  for (int m = 0; m < 2; m++) {
    lsum[m] += __shfl_xor(lsum[m], 16);
    lsum[m] += __shfl_xor(lsum[m], 32);
  }

  if (wave == 1) {
#pragma unroll
    for (int m = 0; m < 2; m++) {
#pragma unroll
      for (int dt = 0; dt < 8; dt++)
        *(f32x4*)&Ex[(m * 16 + l16) * 132 + dt * 16 + quad * 4] = o[m][dt];
      if (lane < 16) Ex[(m * 16 + l16) * 132 + 128] = lsum[m];
    }
  }
  __syncthreads();
  if (wave == 0) {
#pragma unroll
    for (int m = 0; m < 2; m++) {
      float lt = lsum[m] + Ex[(m * 16 + l16) * 132 + 128];
      float inv = 1.0f / lt;
      size_t base = (size_t)(q0 + m * 16 + l16) * HIDDEN + h * HD;
#pragma unroll
      for (int dt = 0; dt < 8; dt++) {
        f32x4 p = *(const f32x4*)&Ex[(m * 16 + l16) * 132 + dt * 16 + quad * 4];
        float v0 = (o[m][dt][0] + p[0]) * inv;
        float v1 = (o[m][dt][1] + p[1]) * inv;
        float v2 = (o[m][dt][2] + p[2]) * inv;
        float v3 = (o[m][dt][3] + p[3]) * inv;
        u32 w0 = ((u32)f2bf(v1) << 16) | f2bf(v0);
        u32 w1 = ((u32)f2bf(v3) << 16) | f2bf(v2);
        uint2 wv; wv.x = w0; wv.y = w1;
        *(uint2*)&attn_out[base + dt * 16 + quad * 4] = wv;
      }
    }
  }
}

// ---------------- launch ----------------
extern "C" void kernel_launch(void* const* d_in, const int* in_sizes, int n_in,
                              void* d_out, int out_size, void* d_ws, size_t ws_size,
                              hipStream_t stream) {
  const float* x  = (const float*)d_in[0];
  const int* pos  = (const int*)d_in[1];
  const float* Wq = (const float*)d_in[3];
  const float* Wk = (const float*)d_in[4];
  const float* Wv = (const float*)d_in[5];
  const float* Wo = (const float*)d_in[6];
  float* out = (float*)d_out;

  u16* x_bf    = (u16*)d_ws;                                  // 2048*4096
  u16* Wqkv_bf = x_bf + (size_t)SEQ * HIDDEN;                 // 6144*4096
  u16* qkv_bf  = Wqkv_bf + (size_t)QKV_N * HIDDEN;            // 2048*6144
  u16* attn_bf = qkv_bf + (size_t)SEQ * QKV_N;                // 2048*4096
  u16* Wo_bf   = attn_bf + (size_t)SEQ * HIDDEN;              // 4096*4096
  u16* vt_bf   = x_bf;   // reuse x_bf region (dead after gemm1); 1024*2048 fits

  auto cvt = [&](const float* s, u16* d, size_t n) {
    int n8 = (int)(n / 8);
    cvt_f32_bf16<<<(n8 + 255) / 256, 256, 0, stream>>>(s, d, n8);
  };
  cvt(x,  x_bf,    (size_t)SEQ * HIDDEN);
  cvt(Wq, Wqkv_bf,                         (size_t)4096 * 4096);
  cvt(Wk, Wqkv_bf + (size_t)4096 * 4096,   (size_t)1024 * 4096);
  cvt(Wv, Wqkv_bf + (size_t)5120 * 4096,   (size_t)1024 * 4096);
  cvt(Wo, Wo_bf,   (size_t)4096 * 4096);

  // GEMM1: 2048x6144x4096, tile 256x192 -> 256 blocks (full chip)
  gemm8p<0, 8, 3><<<dim3(256), 512, 0, stream>>>(x_bf, Wqkv_bf, qkv_bf, SEQ, QKV_N, HIDDEN);

  int rope_threads = SEQ * 40 * 64;
  rope_kernel<<<rope_threads / 256, 256, 0, stream>>>(qkv_bf, pos);

  dim3 gt(SEQ / 64, 1024 / 64);
  transpose_v<<<gt, 256, 0, stream>>>(qkv_bf, vt_bf);

  attn_kernel<<<2048, 128, 0, stream>>>(qkv_bf, vt_bf, attn_bf);

  // GEMM3: 2048x4096x4096, tile 128x256 -> 16*16 = 256 blocks (full chip)
  gemm8p<1, 4, 4><<<dim3(256), 512, 0, stream>>>(attn_bf, Wo_bf, out, SEQ, HIDDEN, HIDDEN);
}